// Round 3
// baseline (358.691 us; speedup 1.0000x reference)
//
#include <hip/hip_runtime.h>
#include <hip/hip_bf16.h>
#include <math.h>

#define N_PTS 32768
#define IN_F  256
#define NUM_CAT 16
#define CF    4096
#define NSEG  6
#define OUTK  50
#define BN_EPS 1e-5f

// ---- ws layout (float offsets). Fixed region first, K-split partials after.
#define OFF_G     0u         // 256*256
#define OFF_FBAR  65536u     // 256
#define OFF_SCALE 65792u     // 4096
#define OFF_SHIFT 69888u     // 4096
#define OFF_INT   73984u     // int region: 67 + 32768 ints = 32835 -> ends 106819
#define OFF_GP    106832u    // Gram partials: 10 tiles * nchunk * 64*64 floats
// col-sum partials at OFF_GP + 40960*nchunk (nchunk*256 floats)
// int offsets (in ints, relative to OFF_INT)
#define IO_COUNTS 0
#define IO_CATOFF 16
#define IO_TILEST 33
#define IO_NTILES 50
#define IO_CURSOR 51
#define IO_ORDER  67

// direct global->LDS staging, 16B per lane (dest = wave-uniform base + lane*16)
__device__ __forceinline__ void gload_lds16(const float* g, float* l) {
    __builtin_amdgcn_global_load_lds(
        (const __attribute__((address_space(1))) void*)g,
        (__attribute__((address_space(3))) void*)l,
        16, 0, 0);
}

// ============ K1: symmetric Gram partials (split-K) + column-sum partials ============
__global__ __launch_bounds__(256) void k1_gram(const float* __restrict__ F,
                                               float* __restrict__ ws,
                                               int nchunk, int rpc) {
    const int TI[10] = {0,0,0,0,1,1,1,2,2,3};
    const int TJ[10] = {0,1,2,3,1,2,3,2,3,3};
    const int t     = blockIdx.x % 10;
    const int chunk = blockIdx.x / 10;
    const int i0 = TI[t] * 64, j0 = TJ[t] * 64;
    const bool diag = (TI[t] == TJ[t]);
    const int r0 = chunk * rpc;
    const int tid = threadIdx.x;

    __shared__ __align__(16) float Alds[32][64];
    __shared__ __align__(16) float Blds[32][64];

    float acc[4][4] = {};
    float colacc = 0.f;
    const int tm = tid & 15, tn = tid >> 4;   // 4x4 micro-tile
    const int kk0 = tid >> 4, sg = tid & 15;  // staging coords (32 rows x 16 float4 segs)

    float4 pa0, pa1, pb0, pb1;
    {   // preload kb = 0
        const float* ra = &F[(size_t)r0 * IN_F];
        pa0 = *(const float4*)&ra[(size_t)(kk0)      * IN_F + i0 + sg * 4];
        pa1 = *(const float4*)&ra[(size_t)(kk0 + 16) * IN_F + i0 + sg * 4];
        pb0 = *(const float4*)&ra[(size_t)(kk0)      * IN_F + j0 + sg * 4];
        pb1 = *(const float4*)&ra[(size_t)(kk0 + 16) * IN_F + j0 + sg * 4];
    }
    for (int kb = 0; kb < rpc; kb += 32) {
        __syncthreads();
        *(float4*)&Alds[kk0][sg * 4]      = pa0;
        *(float4*)&Alds[kk0 + 16][sg * 4] = pa1;
        *(float4*)&Blds[kk0][sg * 4]      = pb0;
        *(float4*)&Blds[kk0 + 16][sg * 4] = pb1;
        __syncthreads();
        if (kb + 32 < rpc) {   // prefetch next slab while computing this one
            const float* ra = &F[(size_t)(r0 + kb + 32) * IN_F];
            pa0 = *(const float4*)&ra[(size_t)(kk0)      * IN_F + i0 + sg * 4];
            pa1 = *(const float4*)&ra[(size_t)(kk0 + 16) * IN_F + i0 + sg * 4];
            pb0 = *(const float4*)&ra[(size_t)(kk0)      * IN_F + j0 + sg * 4];
            pb1 = *(const float4*)&ra[(size_t)(kk0 + 16) * IN_F + j0 + sg * 4];
        }
#pragma unroll 8
        for (int kk = 0; kk < 32; kk++) {
            float4 av = *(const float4*)&Alds[kk][tm * 4];
            float4 bv = *(const float4*)&Blds[kk][tn * 4];
            float a_[4] = {av.x, av.y, av.z, av.w};
            float b_[4] = {bv.x, bv.y, bv.z, bv.w};
#pragma unroll
            for (int i = 0; i < 4; i++)
#pragma unroll
                for (int j = 0; j < 4; j++) acc[i][j] += a_[i] * b_[j];
        }
        if (diag && tid < 64) {
#pragma unroll 8
            for (int kk = 0; kk < 32; kk++) colacc += Alds[kk][tid];
        }
    }
    float* Gp = ws + OFF_GP + (size_t)(t * nchunk + chunk) * 4096;
#pragma unroll
    for (int i = 0; i < 4; i++)
#pragma unroll
        for (int j = 0; j < 4; j++)
            Gp[(tm * 4 + i) * 64 + tn * 4 + j] = acc[i][j];
    if (diag && tid < 64)
        ws[OFF_GP + 40960u * (size_t)nchunk + (size_t)chunk * 256 + i0 + tid] = colacc;
}

// ============ K2a: reduce partials -> G (symmetric reconstruct), colsums -> fbar ============
__global__ __launch_bounds__(256) void k2a_reduce(float* __restrict__ ws, int nchunk) {
    const int tid = threadIdx.x;
    const int e = blockIdx.x * 256 + tid;      // 0..65535
    int a = e >> 8, b = e & 255;
    int i = a >> 6, j = b >> 6, x = a & 63, y = b & 63;
    if (i > j) { int s1 = i; i = j; j = s1; int s2 = x; x = y; y = s2; }
    const int t = i * (7 - i) / 2 + j;
    const float* Gp = ws + OFF_GP + (size_t)t * nchunk * 4096;
    float s = 0.f;
    for (int c = 0; c < nchunk; c++) s += Gp[(size_t)c * 4096 + x * 64 + y];
    ws[OFF_G + e] = s;
    if (blockIdx.x == 0) {
        const float* CS = ws + OFF_GP + 40960u * (size_t)nchunk;
        float fs = 0.f;
        for (int c = 0; c < nchunk; c++) fs += CS[c * 256 + tid];
        ws[OFF_FBAR + tid] = fs * (1.0f / N_PTS);
        int* wi = (int*)(ws + OFF_INT);
        if (tid < 16) wi[IO_COUNTS + tid] = 0;
    }
}

// ============ K2b: per-column mu/var -> scale/shift ============
__global__ __launch_bounds__(256) void k2b_stats(const float* __restrict__ W1,
                                                 const float* __restrict__ gamma,
                                                 const float* __restrict__ beta,
                                                 float* __restrict__ ws) {
    const int tid = threadIdx.x;
    const int j0 = blockIdx.x * 16;
    __shared__ __align__(16) float wl[16][256];
    __shared__ float pw[16][8];
#pragma unroll
    for (int q = 0; q < 4; q++) {
        float4 v = *(const float4*)&W1[(size_t)tid * CF + j0 + q * 4];
        wl[q * 4 + 0][tid] = v.x; wl[q * 4 + 1][tid] = v.y;
        wl[q * 4 + 2][tid] = v.z; wl[q * 4 + 3][tid] = v.w;
    }
    __syncthreads();
    float acc[16];
#pragma unroll
    for (int jj = 0; jj < 16; jj++) acc[jj] = 0.f;
    const float* G = ws + OFF_G;
    for (int b = 0; b < 256; b++) {           // s_a = sum_b G[b][a] * w[jj][b]
        float g = G[b * 256 + tid];
#pragma unroll
        for (int jj = 0; jj < 16; jj++) acc[jj] += g * wl[jj][b];
    }
    float fb = ws[OFF_FBAR + tid];
    const int lane = tid & 63, wave = tid >> 6;
#pragma unroll
    for (int jj = 0; jj < 16; jj++) {
        float w = wl[jj][tid];
        float v = w * acc[jj];                // -> w^T G w
        float m = fb * w;                     // -> mu = fbar . w
#pragma unroll
        for (int off = 32; off >= 1; off >>= 1) {
            v += __shfl_xor(v, off);
            m += __shfl_xor(m, off);
        }
        if (lane == 0) { pw[jj][wave * 2] = v; pw[jj][wave * 2 + 1] = m; }
    }
    __syncthreads();
    if (tid < 16) {
        int jj = tid;
        float v = 0.f, m = 0.f;
        for (int w2 = 0; w2 < 4; w2++) { v += pw[jj][w2 * 2]; m += pw[jj][w2 * 2 + 1]; }
        float mu  = m;
        float var = v * (1.0f / N_PTS) - mu * mu;
        float sc  = gamma[j0 + jj] * rsqrtf(var + BN_EPS);
        float sh  = beta[j0 + jj] - mu * sc;
        ws[OFF_SCALE + j0 + jj] = sc;
        ws[OFF_SHIFT + j0 + jj] = sh;
    }
}

// ============ K3: category histogram ============
__global__ __launch_bounds__(256) void k3_hist(const int* __restrict__ cats,
                                               float* __restrict__ ws) {
    __shared__ int h[16];
    int tid = threadIdx.x;
    if (tid < 16) h[tid] = 0;
    __syncthreads();
    for (int n = blockIdx.x * 256 + tid; n < N_PTS; n += 64 * 256)
        atomicAdd(&h[cats[n]], 1);
    __syncthreads();
    int* wi = (int*)(ws + OFF_INT);
    if (tid < 16) atomicAdd(&wi[IO_COUNTS + tid], h[tid]);
}

// ============ K4: prefix sums (serial, tiny) ============
__global__ void k4_prefix(float* __restrict__ ws) {
    int* wi = (int*)(ws + OFF_INT);
    if (threadIdx.x == 0) {
        int co = 0, ts = 0;
        wi[IO_CATOFF] = 0; wi[IO_TILEST] = 0;
        for (int c = 0; c < 16; c++) {
            int cnt = wi[IO_COUNTS + c];
            wi[IO_CURSOR + c] = co;
            co += cnt; ts += (cnt + 63) >> 6;
            wi[IO_CATOFF + c + 1] = co;
            wi[IO_TILEST + c + 1] = ts;
        }
        wi[IO_NTILES] = ts;
    }
}

// ============ K4b: scatter point ids grouped by category ============
__global__ __launch_bounds__(256) void k4b_scatter(const int* __restrict__ cats,
                                                   float* __restrict__ ws) {
    int* wi = (int*)(ws + OFF_INT);
    for (int n = blockIdx.x * 256 + threadIdx.x; n < N_PTS; n += 64 * 256) {
        int c = cats[n];
        int idx = atomicAdd(&wi[IO_CURSOR + c], 1);
        wi[IO_ORDER + idx] = n;
    }
}

// ============ K5: per-category GEMM + BN + LeakyReLU + Wc + log_softmax + scatter ============
// W1 slab staged via global_load_lds (no VGPR round-trip, no spill); F rows via
// small register prefetch (2 x float4 per thread).
__global__ __launch_bounds__(256) void k5_main(const float* __restrict__ F,
                                               const float* __restrict__ W1,
                                               const float* __restrict__ Wc,
                                               const float* __restrict__ bias,
                                               const int* __restrict__ shifts,
                                               const int* __restrict__ seg_lens,
                                               const float* __restrict__ ws,
                                               float* __restrict__ out) {
    const int* wi = (const int*)(ws + OFF_INT);
    const int t = blockIdx.x;
    if (t >= wi[IO_NTILES]) return;
    int c = 0;
    while (!(t >= wi[IO_TILEST + c] && t < wi[IO_TILEST + c + 1])) c++;
    const int lt = t - wi[IO_TILEST + c];
    const int base = wi[IO_CATOFF + c] + lt * 64;
    const int npts = min(64, wi[IO_COUNTS + c] - lt * 64);
    const int tid = threadIdx.x;
    const int wv = tid >> 6, ln = tid & 63;

    __shared__ __align__(16) float Wlds[32][256];   // linear (gload_lds dest); reused as red[] in epilogue
    __shared__ __align__(16) float Flds[32][65];
    __shared__ float scl[256], shl[256];
    __shared__ float wcl[256 * 6];
    __shared__ int plds[64];

    if (tid < 64) plds[tid] = wi[IO_ORDER + base + min(tid, npts - 1)];
    scl[tid] = ws[OFF_SCALE + c * 256 + tid];
    shl[tid] = ws[OFF_SHIFT + c * 256 + tid];
#pragma unroll
    for (int i = 0; i < 6; i++) wcl[tid + i * 256] = Wc[(size_t)c * 1536 + tid + i * 256];
    __syncthreads();

    const int tm = tid & 15, tn = tid >> 4;   // 4 pts x 16 cols per thread
    const int fm = tid >> 2, fsg = tid & 3;   // F staging coords
    const float* W1c = W1 + (size_t)c * 256;
    float acc[4][16] = {};

    float4 pf0, pf1;
    {   // preload F slab k0 = 0 (plds valid after the setup barrier above)
        const float* fsrc = &F[(size_t)plds[fm] * IN_F + fsg * 8];
        pf0 = *(const float4*)fsrc;
        pf1 = *(const float4*)(fsrc + 4);
    }
    for (int k0 = 0; k0 < 256; k0 += 32) {
        if (k0) __syncthreads();              // prev compute done before overwrite
        // stage W1 slab: wave wv stages rows wv*8 .. wv*8+7, 1024B per instruction
#pragma unroll
        for (int r = 0; r < 8; r++) {
            const int kk = wv * 8 + r;
            gload_lds16(&W1c[(size_t)(k0 + kk) * CF + ln * 4], &Wlds[kk][0]);
        }
        // write prefetched F rows (transposed)
        Flds[fsg * 8 + 0][fm] = pf0.x; Flds[fsg * 8 + 1][fm] = pf0.y;
        Flds[fsg * 8 + 2][fm] = pf0.z; Flds[fsg * 8 + 3][fm] = pf0.w;
        Flds[fsg * 8 + 4][fm] = pf1.x; Flds[fsg * 8 + 5][fm] = pf1.y;
        Flds[fsg * 8 + 6][fm] = pf1.z; Flds[fsg * 8 + 7][fm] = pf1.w;
        __syncthreads();                      // drains vmcnt (gload_lds) + lgkm
        if (k0 + 32 < 256) {                  // prefetch next F slab under compute
            const float* fsrc = &F[(size_t)plds[fm] * IN_F + (k0 + 32) + fsg * 8];
            pf0 = *(const float4*)fsrc;
            pf1 = *(const float4*)(fsrc + 4);
        }
#pragma unroll 4
        for (int kk = 0; kk < 32; kk++) {
            float4 f4 = *(const float4*)&Flds[kk][tm * 4];
            float f_[4] = {f4.x, f4.y, f4.z, f4.w};
#pragma unroll
            for (int q = 0; q < 4; q++) {
                float4 w4 = *(const float4*)&Wlds[kk][tn * 16 + q * 4];
                float w_[4] = {w4.x, w4.y, w4.z, w4.w};
#pragma unroll
                for (int i = 0; i < 4; i++)
#pragma unroll
                    for (int u = 0; u < 4; u++)
                        acc[i][q * 4 + u] += f_[i] * w_[u];
            }
        }
    }

    // epilogue: BN + LeakyReLU + partial logits vs Wc
    float pl[4][6];
#pragma unroll
    for (int i = 0; i < 4; i++)
#pragma unroll
        for (int s = 0; s < 6; s++) pl[i][s] = 0.f;
#pragma unroll
    for (int j = 0; j < 16; j++) {
        int n = tn * 16 + j;
        float sc = scl[n], sh = shl[n];
#pragma unroll
        for (int i = 0; i < 4; i++) {
            float x = acc[i][j] * sc + sh;
            x = (x >= 0.f) ? x : 0.2f * x;
#pragma unroll
            for (int s = 0; s < 6; s++) pl[i][s] += x * wcl[n * 6 + s];
        }
    }
    __syncthreads();                          // Wlds now free for reuse
    float* red = &Wlds[0][0];                 // 16*64*6 = 6144 floats
#pragma unroll
    for (int i = 0; i < 4; i++)
#pragma unroll
        for (int s = 0; s < 6; s++)
            red[(tn * 64 + tm * 4 + i) * 6 + s] = pl[i][s];
    __syncthreads();

    if (tid < 64 && tid < npts) {
        const int m = tid;
        float lg[6];
#pragma unroll
        for (int s = 0; s < 6; s++) lg[s] = bias[s];
        for (int w = 0; w < 16; w++)
#pragma unroll
            for (int s = 0; s < 6; s++) lg[s] += red[(w * 64 + m) * 6 + s];
        float mx = lg[0];
#pragma unroll
        for (int s = 1; s < 6; s++) mx = fmaxf(mx, lg[s]);
        float se = 0.f;
#pragma unroll
        for (int s = 0; s < 6; s++) se += expf(lg[s] - mx);
        float lse = mx + logf(se);
        const int pid = plds[m];
        const int sh = shifts[c], ln2 = seg_lens[c];
        float* orow = out + (size_t)pid * OUTK;
        for (int k = 0; k < OUTK; k++) {
            int j = k - sh;
            orow[k] = (j >= 0 && j < ln2) ? (lg[j] - lse) : 0.f;
        }
    }
}

extern "C" void kernel_launch(void* const* d_in, const int* in_sizes, int n_in,
                              void* d_out, int out_size, void* d_ws, size_t ws_size,
                              hipStream_t stream) {
    const float* F      = (const float*)d_in[0];
    const float* W1     = (const float*)d_in[1];
    const float* gamma  = (const float*)d_in[2];
    const float* beta   = (const float*)d_in[3];
    const float* Wc     = (const float*)d_in[4];
    const float* bias   = (const float*)d_in[5];
    const int*  cats    = (const int*)d_in[6];
    const int*  shifts  = (const int*)d_in[7];
    const int*  seglens = (const int*)d_in[8];
    float* out = (float*)d_out;
    float* ws  = (float*)d_ws;

    // pick largest K-split that fits ws: bytes(n) = (OFF_GP + 41216*n)*4
    int nchunk = 32;
    if      (ws_size >= ((size_t)OFF_GP + 41216ull * 256) * 4) nchunk = 256;
    else if (ws_size >= ((size_t)OFF_GP + 41216ull * 128) * 4) nchunk = 128;
    else if (ws_size >= ((size_t)OFF_GP + 41216ull *  64) * 4) nchunk = 64;
    const int rpc = N_PTS / nchunk;

    hipLaunchKernelGGL(k1_gram,     dim3(10 * nchunk), dim3(256), 0, stream, F, ws, nchunk, rpc);
    hipLaunchKernelGGL(k2a_reduce,  dim3(256), dim3(256), 0, stream, ws, nchunk);
    hipLaunchKernelGGL(k2b_stats,   dim3(256), dim3(256), 0, stream, W1, gamma, beta, ws);
    hipLaunchKernelGGL(k3_hist,     dim3(64),  dim3(256), 0, stream, cats, ws);
    hipLaunchKernelGGL(k4_prefix,   dim3(1),   dim3(64),  0, stream, ws);
    hipLaunchKernelGGL(k4b_scatter, dim3(64),  dim3(256), 0, stream, cats, ws);
    hipLaunchKernelGGL(k5_main,     dim3(528), dim3(256), 0, stream,
                       F, W1, Wc, bias, shifts, seglens, ws, out);
}

// Round 4
// 221.657 us; speedup vs baseline: 1.6182x; 1.6182x over previous
//
#include <hip/hip_runtime.h>
#include <hip/hip_bf16.h>
#include <math.h>

#define N_PTS 32768
#define IN_F  256
#define NUM_CAT 16
#define CF    4096
#define NSEG  6
#define OUTK  50
#define BN_EPS 1e-5f

typedef unsigned short u16;
typedef __attribute__((ext_vector_type(8))) short bf16x8;
typedef __attribute__((ext_vector_type(4))) float f32x4;
typedef __attribute__((ext_vector_type(8))) unsigned short u16x8;

// ---- ws layout (float offsets) ----
#define OFF_G     0u          // 256*256
#define OFF_FBAR  65536u      // 256
#define OFF_SCALE 65792u      // 4096
#define OFF_SHIFT 69888u      // 4096
#define OFF_INT   73984u      // 67 + 32768 ints -> ends 106819
#define OFF_FB    106832u     // F in bf16: 32768*256 u16 = 4194304 floats
#define OFF_W1T   4301136u    // W1 transposed bf16 [16][256 n][256 k] = 524288 floats
#define OFF_GP    4825424u    // partials: [chunk][41216] (10*4096 gram + 256 colsum)
// total floats = OFF_GP + 41216*nchunk ; nchunk=128 -> 40.4 MB
// int offsets (in ints, relative to OFF_INT)
#define IO_COUNTS 0
#define IO_CATOFF 16
#define IO_TILEST 33
#define IO_NTILES 50
#define IO_CURSOR 51
#define IO_ORDER  67

__device__ __forceinline__ void gload_lds16(const void* g, void* l) {
    __builtin_amdgcn_global_load_lds(
        (const __attribute__((address_space(1))) void*)g,
        (__attribute__((address_space(3))) void*)l,
        16, 0, 0);
}
__device__ __forceinline__ u16 f2bf(float f) {
    unsigned int u = __float_as_uint(f);
    return (u16)((u + 0x7FFF + ((u >> 16) & 1)) >> 16);
}
__device__ __forceinline__ float bf2f(u16 h) {
    return __uint_as_float((unsigned int)h << 16);
}

// ============ K0a: F -> bf16 ============
__global__ __launch_bounds__(256) void k0a_cvt(const float* __restrict__ F,
                                               u16* __restrict__ Fb) {
    int i = (blockIdx.x * 256 + threadIdx.x) * 8;
    float4 v0 = *(const float4*)&F[i];
    float4 v1 = *(const float4*)&F[i + 4];
    u16x8 o;
    o[0] = f2bf(v0.x); o[1] = f2bf(v0.y); o[2] = f2bf(v0.z); o[3] = f2bf(v0.w);
    o[4] = f2bf(v1.x); o[5] = f2bf(v1.y); o[6] = f2bf(v1.z); o[7] = f2bf(v1.w);
    *(u16x8*)&Fb[i] = o;
}

// ============ K0b: W1 [256][4096] -> W1T bf16 [c][n][k] ============
__global__ __launch_bounds__(256) void k0b_w1t(const float* __restrict__ W1,
                                               u16* __restrict__ W1T) {
    __shared__ u16 T[64][65];
    const int kb = blockIdx.x & 3, jb = blockIdx.x >> 2;
    const int tid = threadIdx.x;
    {
        int kk = tid >> 2, j4 = (tid & 3) * 16;
        const float* src = &W1[(size_t)(kb * 64 + kk) * CF + jb * 64 + j4];
#pragma unroll
        for (int q = 0; q < 4; q++) {
            float4 v = *(const float4*)&src[q * 4];
            T[kk][j4 + q * 4 + 0] = f2bf(v.x); T[kk][j4 + q * 4 + 1] = f2bf(v.y);
            T[kk][j4 + q * 4 + 2] = f2bf(v.z); T[kk][j4 + q * 4 + 3] = f2bf(v.w);
        }
    }
    __syncthreads();
    {
        int jj = tid >> 2, ks = (tid & 3) * 16;
        int c = jb >> 2, n = (jb & 3) * 64 + jj;
        u16* dst = &W1T[((size_t)(c * 256 + n)) * 256 + kb * 64 + ks];
        u16x8 o0, o1;
#pragma unroll
        for (int m = 0; m < 8; m++) { o0[m] = T[ks + m][jj]; o1[m] = T[ks + 8 + m][jj]; }
        *(u16x8*)dst = o0;
        *(u16x8*)&dst[8] = o1;
    }
}

// ============ K1: symmetric Gram partials (split-K, fp32) ============
__global__ __launch_bounds__(256) void k1_gram(const float* __restrict__ F,
                                               float* __restrict__ ws,
                                               int nchunk, int rpc) {
    const int TI[10] = {0,0,0,0,1,1,1,2,2,3};
    const int TJ[10] = {0,1,2,3,1,2,3,2,3,3};
    const int t     = blockIdx.x % 10;
    const int chunk = blockIdx.x / 10;
    const int i0 = TI[t] * 64, j0 = TJ[t] * 64;
    const bool diag = (TI[t] == TJ[t]);
    const int r0 = chunk * rpc;
    const int tid = threadIdx.x;

    __shared__ __align__(16) float Alds[32][64];
    __shared__ __align__(16) float Blds[32][64];

    float acc[4][4] = {};
    float colacc = 0.f;
    const int tm = tid & 15, tn = tid >> 4;
    const int kk0 = tid >> 4, sg = tid & 15;

    float4 pa0, pa1, pb0, pb1;
    {
        const float* ra = &F[(size_t)r0 * IN_F];
        pa0 = *(const float4*)&ra[(size_t)(kk0)      * IN_F + i0 + sg * 4];
        pa1 = *(const float4*)&ra[(size_t)(kk0 + 16) * IN_F + i0 + sg * 4];
        pb0 = *(const float4*)&ra[(size_t)(kk0)      * IN_F + j0 + sg * 4];
        pb1 = *(const float4*)&ra[(size_t)(kk0 + 16) * IN_F + j0 + sg * 4];
    }
    for (int kb = 0; kb < rpc; kb += 32) {
        __syncthreads();
        *(float4*)&Alds[kk0][sg * 4]      = pa0;
        *(float4*)&Alds[kk0 + 16][sg * 4] = pa1;
        *(float4*)&Blds[kk0][sg * 4]      = pb0;
        *(float4*)&Blds[kk0 + 16][sg * 4] = pb1;
        __syncthreads();
        if (kb + 32 < rpc) {
            const float* ra = &F[(size_t)(r0 + kb + 32) * IN_F];
            pa0 = *(const float4*)&ra[(size_t)(kk0)      * IN_F + i0 + sg * 4];
            pa1 = *(const float4*)&ra[(size_t)(kk0 + 16) * IN_F + i0 + sg * 4];
            pb0 = *(const float4*)&ra[(size_t)(kk0)      * IN_F + j0 + sg * 4];
            pb1 = *(const float4*)&ra[(size_t)(kk0 + 16) * IN_F + j0 + sg * 4];
        }
#pragma unroll 8
        for (int kk = 0; kk < 32; kk++) {
            float4 av = *(const float4*)&Alds[kk][tm * 4];
            float4 bv = *(const float4*)&Blds[kk][tn * 4];
            float a_[4] = {av.x, av.y, av.z, av.w};
            float b_[4] = {bv.x, bv.y, bv.z, bv.w};
#pragma unroll
            for (int i = 0; i < 4; i++)
#pragma unroll
                for (int j = 0; j < 4; j++) acc[i][j] += a_[i] * b_[j];
        }
        if (diag && tid < 64) {
#pragma unroll 8
            for (int kk = 0; kk < 32; kk++) colacc += Alds[kk][tid];
        }
    }
    float* Gp = ws + OFF_GP + (size_t)chunk * 41216 + t * 4096;
#pragma unroll
    for (int i = 0; i < 4; i++)
#pragma unroll
        for (int j = 0; j < 4; j++)
            Gp[(tm * 4 + i) * 64 + tn * 4 + j] = acc[i][j];
    if (diag && tid < 64)
        ws[OFF_GP + (size_t)chunk * 41216 + 40960 + i0 + tid] = colacc;
}

// ============ K2a: coalesced column-sum of partials ============
__global__ __launch_bounds__(256) void k2a_reduce(float* __restrict__ ws, int nchunk) {
    const int TI[10] = {0,0,0,0,1,1,1,2,2,3};
    const int TJ[10] = {0,1,2,3,1,2,3,2,3,3};
    const int tid = threadIdx.x;
    const int e = blockIdx.x * 256 + tid;      // 0..41215
    const float* p = ws + OFF_GP + e;
    float s = 0.f;
#pragma unroll 8
    for (int c = 0; c < nchunk; c++) s += p[(size_t)c * 41216];
    if (e < 40960) {
        int t = e >> 12, x = (e >> 6) & 63, y = e & 63;
        int a = TI[t] * 64 + x, b = TJ[t] * 64 + y;
        ws[OFF_G + a * 256 + b] = s;
        ws[OFF_G + b * 256 + a] = s;
    } else {
        ws[OFF_FBAR + (e - 40960)] = s * (1.0f / N_PTS);
        int* wi = (int*)(ws + OFF_INT);
        if (tid < 16) wi[IO_COUNTS + tid] = 0;
    }
}

// ============ K2b: per-column mu/var -> scale/shift ============
__global__ __launch_bounds__(256) void k2b_stats(const float* __restrict__ W1,
                                                 const float* __restrict__ gamma,
                                                 const float* __restrict__ beta,
                                                 float* __restrict__ ws) {
    const int tid = threadIdx.x;
    const int j0 = blockIdx.x * 16;
    __shared__ __align__(16) float wl[16][256];
    __shared__ float pw[16][8];
#pragma unroll
    for (int q = 0; q < 4; q++) {
        float4 v = *(const float4*)&W1[(size_t)tid * CF + j0 + q * 4];
        wl[q * 4 + 0][tid] = v.x; wl[q * 4 + 1][tid] = v.y;
        wl[q * 4 + 2][tid] = v.z; wl[q * 4 + 3][tid] = v.w;
    }
    __syncthreads();
    float acc[16];
#pragma unroll
    for (int jj = 0; jj < 16; jj++) acc[jj] = 0.f;
    const float* G = ws + OFF_G;
    for (int b = 0; b < 256; b++) {
        float g = G[b * 256 + tid];
#pragma unroll
        for (int jj = 0; jj < 16; jj++) acc[jj] += g * wl[jj][b];
    }
    float fb = ws[OFF_FBAR + tid];
    const int lane = tid & 63, wave = tid >> 6;
#pragma unroll
    for (int jj = 0; jj < 16; jj++) {
        float v = wl[jj][tid] * acc[jj];
        float m = fb * wl[jj][tid];
#pragma unroll
        for (int off = 32; off >= 1; off >>= 1) {
            v += __shfl_xor(v, off);
            m += __shfl_xor(m, off);
        }
        if (lane == 0) { pw[jj][wave * 2] = v; pw[jj][wave * 2 + 1] = m; }
    }
    __syncthreads();
    if (tid < 16) {
        int jj = tid;
        float v = 0.f, m = 0.f;
        for (int w2 = 0; w2 < 4; w2++) { v += pw[jj][w2 * 2]; m += pw[jj][w2 * 2 + 1]; }
        float mu  = m;
        float var = v * (1.0f / N_PTS) - mu * mu;
        float sc  = gamma[j0 + jj] * rsqrtf(var + BN_EPS);
        float sh  = beta[j0 + jj] - mu * sc;
        ws[OFF_SCALE + j0 + jj] = sc;
        ws[OFF_SHIFT + j0 + jj] = sh;
    }
}

// ============ K3/K4/K4b: histogram, prefix, scatter ============
__global__ __launch_bounds__(256) void k3_hist(const int* __restrict__ cats,
                                               float* __restrict__ ws) {
    __shared__ int h[16];
    int tid = threadIdx.x;
    if (tid < 16) h[tid] = 0;
    __syncthreads();
    for (int n = blockIdx.x * 256 + tid; n < N_PTS; n += 64 * 256)
        atomicAdd(&h[cats[n]], 1);
    __syncthreads();
    int* wi = (int*)(ws + OFF_INT);
    if (tid < 16) atomicAdd(&wi[IO_COUNTS + tid], h[tid]);
}

__global__ void k4_prefix(float* __restrict__ ws) {
    int* wi = (int*)(ws + OFF_INT);
    if (threadIdx.x == 0) {
        int co = 0, ts = 0;
        wi[IO_CATOFF] = 0; wi[IO_TILEST] = 0;
        for (int c = 0; c < 16; c++) {
            int cnt = wi[IO_COUNTS + c];
            wi[IO_CURSOR + c] = co;
            co += cnt; ts += (cnt + 63) >> 6;
            wi[IO_CATOFF + c + 1] = co;
            wi[IO_TILEST + c + 1] = ts;
        }
        wi[IO_NTILES] = ts;
    }
}

__global__ __launch_bounds__(256) void k4b_scatter(const int* __restrict__ cats,
                                                   float* __restrict__ ws) {
    int* wi = (int*)(ws + OFF_INT);
    for (int n = blockIdx.x * 256 + threadIdx.x; n < N_PTS; n += 64 * 256) {
        int c = cats[n];
        int idx = atomicAdd(&wi[IO_CURSOR + c], 1);
        wi[IO_ORDER + idx] = n;
    }
}

// ============ K5: bf16-MFMA GEMM + BN + LeakyReLU + Wc + log_softmax + scatter ====
// Block: 64 points x 256 cols. 4 waves, wave w owns cols w*64..w*64+63.
// Fl (LDS bytes 0..32767): [64 pt][256 k] bf16, XOR-swizzled 16B units by (pt&7).
// Wl (32768..65535): 2 x [256 n][32 k] bf16, XOR-swizzled 16B units by (n&3).
// Epilogue reuse: X bf16 [64][272] at 0; red f32 [16][64][6] at 36864.
__global__ __launch_bounds__(256) void k5_mfma(const u16* __restrict__ Fb,
                                               const u16* __restrict__ W1T,
                                               const float* __restrict__ Wc,
                                               const float* __restrict__ bias,
                                               const int* __restrict__ shifts,
                                               const int* __restrict__ seg_lens,
                                               const float* __restrict__ ws,
                                               float* __restrict__ out) {
    const int* wi = (const int*)(ws + OFF_INT);
    const int t = blockIdx.x;
    if (t >= wi[IO_NTILES]) return;
    int c = 0;
    while (!(t >= wi[IO_TILEST + c] && t < wi[IO_TILEST + c + 1])) c++;
    const int lt = t - wi[IO_TILEST + c];
    const int base = wi[IO_CATOFF + c] + lt * 64;
    const int npts = min(64, wi[IO_COUNTS + c] - lt * 64);
    const int tid = threadIdx.x;
    const int wv = tid >> 6, ln = tid & 63;
    const int g = ln >> 4, r16 = ln & 15;

    __shared__ __align__(16) unsigned char U[65536];
    __shared__ float scl[256], shl[256], wcl[1536];
    __shared__ int plds[64];

    if (tid < 64) plds[tid] = wi[IO_ORDER + base + min(tid, npts - 1)];
    scl[tid] = ws[OFF_SCALE + c * 256 + tid];
    shl[tid] = ws[OFF_SHIFT + c * 256 + tid];
#pragma unroll
    for (int i = 0; i < 6; i++) wcl[tid + i * 256] = Wc[(size_t)c * 1536 + tid + i * 256];
    __syncthreads();

    const u16* W1Tc = W1T + (size_t)c * 65536;

    // ---- stage F tile (once): 8 gload steps, pre-swizzled source ----
#pragma unroll
    for (int s = 0; s < 8; s++) {
        int flat = s * 256 + tid;            // 16B unit index
        int pt = flat >> 5, u = flat & 31;
        const u16* src = Fb + (size_t)plds[pt] * 256 + ((u ^ (pt & 7)) << 3);
        gload_lds16(src, U + (size_t)(s * 4 + wv) * 1024);
    }
    // ---- stage W chunk 0 into buf 0 ----
#pragma unroll
    for (int rr = 0; rr < 4; rr++) {
        int n = wv * 64 + rr * 16 + (ln >> 2);
        int q = ln & 3;
        const u16* src = W1Tc + (size_t)n * 256 + 0 + ((q ^ (n & 3)) << 3);
        gload_lds16(src, U + 32768 + (size_t)(wv * 64 + rr * 16) * 64);
    }
    __syncthreads();

    f32x4 acc[4][4];
#pragma unroll
    for (int mt = 0; mt < 4; mt++)
#pragma unroll
        for (int nt = 0; nt < 4; nt++)
#pragma unroll
            for (int i = 0; i < 4; i++) acc[mt][nt][i] = 0.f;

    int cur = 0;
    for (int kc = 0; kc < 8; kc++) {
        if (kc < 7) {   // stage next chunk into other buffer (async across compute)
            int k0 = (kc + 1) * 32;
#pragma unroll
            for (int rr = 0; rr < 4; rr++) {
                int n = wv * 64 + rr * 16 + (ln >> 2);
                int q = ln & 3;
                const u16* src = W1Tc + (size_t)n * 256 + k0 + ((q ^ (n & 3)) << 3);
                gload_lds16(src, U + 32768 + (size_t)(cur ^ 1) * 16384
                                 + (size_t)(wv * 64 + rr * 16) * 64);
            }
        }
        bf16x8 af[4], bf[4];
#pragma unroll
        for (int mt = 0; mt < 4; mt++) {
            int row = mt * 16 + r16;
            int phys = (kc * 4 + g) ^ (row & 7);
            af[mt] = *(const bf16x8*)(U + (size_t)row * 512 + phys * 16);
        }
#pragma unroll
        for (int nt = 0; nt < 4; nt++) {
            int n = wv * 64 + nt * 16 + r16;
            int phys = g ^ (n & 3);
            bf[nt] = *(const bf16x8*)(U + 32768 + (size_t)cur * 16384
                                      + (size_t)n * 64 + phys * 16);
        }
#pragma unroll
        for (int mt = 0; mt < 4; mt++)
#pragma unroll
            for (int nt = 0; nt < 4; nt++)
                acc[mt][nt] = __builtin_amdgcn_mfma_f32_16x16x32_bf16(
                    af[mt], bf[nt], acc[mt][nt], 0, 0, 0);
        __syncthreads();
        cur ^= 1;
    }

    // ---- epilogue phase 1: BN + LeakyReLU -> X bf16 [64][272] ----
    u16* X = (u16*)U;
#pragma unroll
    for (int mt = 0; mt < 4; mt++)
#pragma unroll
        for (int nt = 0; nt < 4; nt++) {
            int col = wv * 64 + nt * 16 + r16;
            float sc = scl[col], sh = shl[col];
#pragma unroll
            for (int i = 0; i < 4; i++) {
                int pt = mt * 16 + g * 4 + i;
                float x = acc[mt][nt][i] * sc + sh;
                x = (x >= 0.f) ? x : 0.2f * x;
                X[pt * 272 + col] = f2bf(x);
            }
        }
    __syncthreads();

    // ---- epilogue phase 2: partial logits vs Wc ----
    const int tm = tid & 15, tn = tid >> 4;
    float pl[4][6];
#pragma unroll
    for (int i = 0; i < 4; i++)
#pragma unroll
        for (int s = 0; s < 6; s++) pl[i][s] = 0.f;
#pragma unroll
    for (int j = 0; j < 16; j++) {
        int n = tn * 16 + j;
#pragma unroll
        for (int i = 0; i < 4; i++) {
            float x = bf2f(X[(tm * 4 + i) * 272 + n]);
#pragma unroll
            for (int s = 0; s < 6; s++) pl[i][s] += x * wcl[n * 6 + s];
        }
    }
    float* red = (float*)(U + 36864);        // [16][64][6], disjoint from X
#pragma unroll
    for (int i = 0; i < 4; i++)
#pragma unroll
        for (int s = 0; s < 6; s++)
            red[(tn * 64 + tm * 4 + i) * 6 + s] = pl[i][s];
    __syncthreads();

    if (tid < 64 && tid < npts) {
        const int m = tid;
        float lg[6];
#pragma unroll
        for (int s = 0; s < 6; s++) lg[s] = bias[s];
        for (int w = 0; w < 16; w++)
#pragma unroll
            for (int s = 0; s < 6; s++) lg[s] += red[(w * 64 + m) * 6 + s];
        float mx = lg[0];
#pragma unroll
        for (int s = 1; s < 6; s++) mx = fmaxf(mx, lg[s]);
        float se = 0.f;
#pragma unroll
        for (int s = 0; s < 6; s++) se += expf(lg[s] - mx);
        float lse = mx + logf(se);
        const int pid = plds[m];
        const int sh = shifts[c], ln2 = seg_lens[c];
        float* orow = out + (size_t)pid * OUTK;
        for (int k = 0; k < OUTK; k++) {
            int j = k - sh;
            orow[k] = (j >= 0 && j < ln2) ? (lg[j] - lse) : 0.f;
        }
    }
}

extern "C" void kernel_launch(void* const* d_in, const int* in_sizes, int n_in,
                              void* d_out, int out_size, void* d_ws, size_t ws_size,
                              hipStream_t stream) {
    const float* F      = (const float*)d_in[0];
    const float* W1     = (const float*)d_in[1];
    const float* gamma  = (const float*)d_in[2];
    const float* beta   = (const float*)d_in[3];
    const float* Wc     = (const float*)d_in[4];
    const float* bias   = (const float*)d_in[5];
    const int*  cats    = (const int*)d_in[6];
    const int*  shifts  = (const int*)d_in[7];
    const int*  seglens = (const int*)d_in[8];
    float* out = (float*)d_out;
    float* ws  = (float*)d_ws;
    u16* Fb  = (u16*)(ws + OFF_FB);
    u16* W1T = (u16*)(ws + OFF_W1T);

    int nchunk = 128;
    if (ws_size < ((size_t)OFF_GP + 41216ull * 128) * 4) nchunk = 64;
    if (ws_size < ((size_t)OFF_GP + 41216ull * 64) * 4)  nchunk = 32;
    const int rpc = N_PTS / nchunk;

    hipLaunchKernelGGL(k0a_cvt,     dim3(4096), dim3(256), 0, stream, F, Fb);
    hipLaunchKernelGGL(k0b_w1t,     dim3(256),  dim3(256), 0, stream, W1, W1T);
    hipLaunchKernelGGL(k1_gram,     dim3(10 * nchunk), dim3(256), 0, stream, F, ws, nchunk, rpc);
    hipLaunchKernelGGL(k2a_reduce,  dim3(161),  dim3(256), 0, stream, ws, nchunk);
    hipLaunchKernelGGL(k2b_stats,   dim3(256),  dim3(256), 0, stream, W1, gamma, beta, ws);
    hipLaunchKernelGGL(k3_hist,     dim3(64),   dim3(256), 0, stream, cats, ws);
    hipLaunchKernelGGL(k4_prefix,   dim3(1),    dim3(64),  0, stream, ws);
    hipLaunchKernelGGL(k4b_scatter, dim3(64),   dim3(256), 0, stream, cats, ws);
    hipLaunchKernelGGL(k5_mfma,     dim3(528),  dim3(256), 0, stream,
                       Fb, W1T, Wc, bias, shifts, seglens, ws, out);
}

// Round 5
// 122.668 us; speedup vs baseline: 2.9241x; 1.8070x over previous
//
#include <hip/hip_runtime.h>
#include <hip/hip_bf16.h>
#include <math.h>

#define N_PTS 32768
#define IN_F  256
#define NUM_CAT 16
#define CF    4096
#define NSEG  6
#define OUTK  50
#define BN_EPS 1e-5f

typedef unsigned short u16;
typedef __attribute__((ext_vector_type(8))) short bf16x8;
typedef __attribute__((ext_vector_type(4))) float f32x4;
typedef __attribute__((ext_vector_type(8))) unsigned short u16x8;

// ---- ws layout (float offsets) ----
#define OFF_G     0u          // 256*256
#define OFF_FBAR  65536u      // 256
#define OFF_SCALE 65792u      // 4096
#define OFF_SHIFT 69888u      // 4096
#define OFF_INT   73984u      // 67 + 32768 ints -> ends 106819
#define OFF_FB    106832u     // F bf16 [32768][256]            (4194304 float slots)
#define OFF_FBT   4301136u    // F^T bf16 [256][32768]           (4194304 float slots)
#define OFF_W1T   8495440u    // W1T bf16 [16][256 n][256 k]     (524288 float slots)
#define OFF_GP    9019728u    // Gram partials [chunk][40960]
// total floats = OFF_GP + 40960*nchunk ; nchunk=64 -> 46.6 MB
#define IO_COUNTS 0
#define IO_CATOFF 16
#define IO_TILEST 33
#define IO_NTILES 50
#define IO_CURSOR 51
#define IO_ORDER  67

__device__ __forceinline__ void gload_lds16(const void* g, void* l) {
    __builtin_amdgcn_global_load_lds(
        (const __attribute__((address_space(1))) void*)g,
        (__attribute__((address_space(3))) void*)l,
        16, 0, 0);
}
__device__ __forceinline__ u16 f2bf(float f) {
    unsigned int u = __float_as_uint(f);
    return (u16)((u + 0x7FFF + ((u >> 16) & 1)) >> 16);
}
__device__ __forceinline__ float bf2f(u16 h) {
    return __uint_as_float((unsigned int)h << 16);
}

// ============ K0: F -> Fb (row-major bf16) AND FbT (transposed bf16) ============
// grid 2048: blockIdx>>2 = 64-pt tile, blockIdx&3 = 64-feat tile
__global__ __launch_bounds__(256) void k0_cvt(const float* __restrict__ F,
                                              u16* __restrict__ Fb,
                                              u16* __restrict__ FbT) {
    const int pb = blockIdx.x >> 2, fb = blockIdx.x & 3;
    const int p0 = pb * 64, f0 = fb * 64;
    const int tid = threadIdx.x;
    __shared__ u16 T[64][72];
    {
        int p = tid >> 2, fq = tid & 3;
        const float* src = &F[(size_t)(p0 + p) * IN_F + f0 + fq * 16];
        u16x8 o0, o1;
        float4 v0 = *(const float4*)&src[0];
        float4 v1 = *(const float4*)&src[4];
        float4 v2 = *(const float4*)&src[8];
        float4 v3 = *(const float4*)&src[12];
        o0[0]=f2bf(v0.x); o0[1]=f2bf(v0.y); o0[2]=f2bf(v0.z); o0[3]=f2bf(v0.w);
        o0[4]=f2bf(v1.x); o0[5]=f2bf(v1.y); o0[6]=f2bf(v1.z); o0[7]=f2bf(v1.w);
        o1[0]=f2bf(v2.x); o1[1]=f2bf(v2.y); o1[2]=f2bf(v2.z); o1[3]=f2bf(v2.w);
        o1[4]=f2bf(v3.x); o1[5]=f2bf(v3.y); o1[6]=f2bf(v3.z); o1[7]=f2bf(v3.w);
        u16* dst = &Fb[(size_t)(p0 + p) * IN_F + f0 + fq * 16];
        *(u16x8*)dst = o0; *(u16x8*)&dst[8] = o1;
        *(u16x8*)&T[p][fq * 16] = o0; *(u16x8*)&T[p][fq * 16 + 8] = o1;
    }
    __syncthreads();
    {
        int f = tid >> 2, pq = tid & 3;
        u16x8 a0, a1;
#pragma unroll
        for (int m = 0; m < 8; m++) { a0[m] = T[pq*16 + m][f]; a1[m] = T[pq*16 + 8 + m][f]; }
        u16* dst = &FbT[(size_t)(f0 + f) * N_PTS + p0 + pq * 16];
        *(u16x8*)dst = a0; *(u16x8*)&dst[8] = a1;
    }
}

// ============ K0b: W1 [256][4096] -> W1T bf16 [c][n][k] ============
__global__ __launch_bounds__(256) void k0b_w1t(const float* __restrict__ W1,
                                               u16* __restrict__ W1T) {
    __shared__ u16 T[64][65];
    const int kb = blockIdx.x & 3, jb = blockIdx.x >> 2;
    const int tid = threadIdx.x;
    {
        int kk = tid >> 2, j4 = (tid & 3) * 16;
        const float* src = &W1[(size_t)(kb * 64 + kk) * CF + jb * 64 + j4];
#pragma unroll
        for (int q = 0; q < 4; q++) {
            float4 v = *(const float4*)&src[q * 4];
            T[kk][j4 + q * 4 + 0] = f2bf(v.x); T[kk][j4 + q * 4 + 1] = f2bf(v.y);
            T[kk][j4 + q * 4 + 2] = f2bf(v.z); T[kk][j4 + q * 4 + 3] = f2bf(v.w);
        }
    }
    __syncthreads();
    {
        int jj = tid >> 2, ks = (tid & 3) * 16;
        int c = jb >> 2, n = (jb & 3) * 64 + jj;
        u16* dst = &W1T[((size_t)(c * 256 + n)) * 256 + kb * 64 + ks];
        u16x8 o0, o1;
#pragma unroll
        for (int m = 0; m < 8; m++) { o0[m] = T[ks + m][jj]; o1[m] = T[ks + 8 + m][jj]; }
        *(u16x8*)dst = o0;
        *(u16x8*)&dst[8] = o1;
    }
}

// ============ K1: Gram via bf16 MFMA (10 symmetric tiles x nchunk K-chunks) ============
// LDS: SA/SB double-buffered [64 rows][64 pts] bf16, 16B-unit XOR swizzle by (row&7),
// staged via global_load_lds with pre-swizzled source (linear dest).
__global__ __launch_bounds__(256) void k1_gram(const u16* __restrict__ FbT,
                                               float* __restrict__ ws,
                                               int nchunk, int Kc) {
    const int TI[10] = {0,0,0,0,1,1,1,2,2,3};
    const int TJ[10] = {0,1,2,3,1,2,3,2,3,3};
    const int t = blockIdx.x % 10, chunk = blockIdx.x / 10;
    const int i0 = TI[t] * 64, j0 = TJ[t] * 64;
    const int r0 = chunk * Kc;
    const int tid = threadIdx.x;
    const int wv = tid >> 6, ln = tid & 63, g = ln >> 4, r16 = ln & 15;
    __shared__ __align__(16) u16 SA[2][4096];
    __shared__ __align__(16) u16 SB[2][4096];

    const int q0 = wv * 2, q1 = wv * 2 + 1;
    const int u_a = ((q0 * 64 + ln) & 7), row_a = (q0 * 64 + ln) >> 3;
    const int u_b = ((q1 * 64 + ln) & 7), row_b = (q1 * 64 + ln) >> 3;
    const int ka = ((u_a ^ (row_a & 7)) << 3), kb2 = ((u_b ^ (row_b & 7)) << 3);

    f32x4 acc[4];
#pragma unroll
    for (int nt = 0; nt < 4; nt++)
#pragma unroll
        for (int i = 0; i < 4; i++) acc[nt][i] = 0.f;

    const int nslab = Kc >> 6;
#define K1_STAGE(s, b)                                                              \
    {   int p0s = r0 + (s) * 64;                                                    \
        gload_lds16(FbT + (size_t)(i0 + row_a) * N_PTS + p0s + ka,                  \
                    (char*)SA[b] + q0 * 1024);                                      \
        gload_lds16(FbT + (size_t)(i0 + row_b) * N_PTS + p0s + kb2,                 \
                    (char*)SA[b] + q1 * 1024);                                      \
        gload_lds16(FbT + (size_t)(j0 + row_a) * N_PTS + p0s + ka,                  \
                    (char*)SB[b] + q0 * 1024);                                      \
        gload_lds16(FbT + (size_t)(j0 + row_b) * N_PTS + p0s + kb2,                 \
                    (char*)SB[b] + q1 * 1024);                                      \
    }

    K1_STAGE(0, 0);
    __syncthreads();
    for (int s = 0; s < nslab; s++) {
        const int b = s & 1;
        if (s + 1 < nslab) K1_STAGE(s + 1, b ^ 1);
#pragma unroll
        for (int ks = 0; ks < 2; ks++) {
            int ph = (ks * 4 + g) ^ (r16 & 7);
            bf16x8 a = *(const bf16x8*)((const char*)SA[b] + (wv * 16 + r16) * 128 + ph * 16);
#pragma unroll
            for (int nt = 0; nt < 4; nt++) {
                int nB = nt * 16 + r16;
                bf16x8 bb = *(const bf16x8*)((const char*)SB[b] + nB * 128 + ph * 16);
                acc[nt] = __builtin_amdgcn_mfma_f32_16x16x32_bf16(a, bb, acc[nt], 0, 0, 0);
            }
        }
        __syncthreads();
    }
    float* Gp = ws + OFF_GP + (size_t)chunk * 40960 + t * 4096;
#pragma unroll
    for (int nt = 0; nt < 4; nt++)
#pragma unroll
        for (int i = 0; i < 4; i++) {
            int row = wv * 16 + g * 4 + i, col = nt * 16 + r16;
            Gp[row * 64 + col] = acc[nt][i];
        }
}

// ============ K1b: column means from FbT; zero category counts ============
__global__ __launch_bounds__(256) void k1b_colsum(const u16* __restrict__ FbT,
                                                  float* __restrict__ ws) {
    const int row = blockIdx.x, tid = threadIdx.x;
    const u16* r = FbT + (size_t)row * N_PTS;
    float s = 0.f;
    for (int i = tid * 8; i < N_PTS; i += 2048) {
        u16x8 v = *(const u16x8*)&r[i];
#pragma unroll
        for (int m = 0; m < 8; m++) s += bf2f(v[m]);
    }
#pragma unroll
    for (int off = 32; off >= 1; off >>= 1) s += __shfl_xor(s, off);
    __shared__ float ps[4];
    if ((tid & 63) == 0) ps[tid >> 6] = s;
    __syncthreads();
    if (tid == 0) ws[OFF_FBAR + row] = (ps[0] + ps[1] + ps[2] + ps[3]) * (1.0f / N_PTS);
    if (blockIdx.x == 0 && tid < 16) ((int*)(ws + OFF_INT))[IO_COUNTS + tid] = 0;
}

// ============ K2a: coalesced reduce of Gram partials -> symmetric G ============
__global__ __launch_bounds__(256) void k2a_reduce(float* __restrict__ ws, int nchunk) {
    const int TI[10] = {0,0,0,0,1,1,1,2,2,3};
    const int TJ[10] = {0,1,2,3,1,2,3,2,3,3};
    const int e = blockIdx.x * 256 + threadIdx.x;   // 0..40959
    const float* p = ws + OFF_GP + e;
    float s = 0.f;
#pragma unroll 8
    for (int c = 0; c < nchunk; c++) s += p[(size_t)c * 40960];
    int t = e >> 12, x = (e >> 6) & 63, y = e & 63;
    int a = TI[t] * 64 + x, b = TJ[t] * 64 + y;
    ws[OFF_G + a * 256 + b] = s;
    ws[OFF_G + b * 256 + a] = s;
}

// ============ K2b: per-column mu/var -> scale/shift ============
__global__ __launch_bounds__(256) void k2b_stats(const float* __restrict__ W1,
                                                 const float* __restrict__ gamma,
                                                 const float* __restrict__ beta,
                                                 float* __restrict__ ws) {
    const int tid = threadIdx.x;
    const int j0 = blockIdx.x * 16;
    __shared__ __align__(16) float wl[16][256];
    __shared__ float pw[16][8];
#pragma unroll
    for (int q = 0; q < 4; q++) {
        float4 v = *(const float4*)&W1[(size_t)tid * CF + j0 + q * 4];
        wl[q * 4 + 0][tid] = v.x; wl[q * 4 + 1][tid] = v.y;
        wl[q * 4 + 2][tid] = v.z; wl[q * 4 + 3][tid] = v.w;
    }
    __syncthreads();
    float acc[16];
#pragma unroll
    for (int jj = 0; jj < 16; jj++) acc[jj] = 0.f;
    const float* G = ws + OFF_G;
    for (int b = 0; b < 256; b++) {
        float g = G[b * 256 + tid];
#pragma unroll
        for (int jj = 0; jj < 16; jj++) acc[jj] += g * wl[jj][b];
    }
    float fb = ws[OFF_FBAR + tid];
    const int lane = tid & 63, wave = tid >> 6;
#pragma unroll
    for (int jj = 0; jj < 16; jj++) {
        float v = wl[jj][tid] * acc[jj];
        float m = fb * wl[jj][tid];
#pragma unroll
        for (int off = 32; off >= 1; off >>= 1) {
            v += __shfl_xor(v, off);
            m += __shfl_xor(m, off);
        }
        if (lane == 0) { pw[jj][wave * 2] = v; pw[jj][wave * 2 + 1] = m; }
    }
    __syncthreads();
    if (tid < 16) {
        int jj = tid;
        float v = 0.f, m = 0.f;
        for (int w2 = 0; w2 < 4; w2++) { v += pw[jj][w2 * 2]; m += pw[jj][w2 * 2 + 1]; }
        float mu  = m;
        float var = v * (1.0f / N_PTS) - mu * mu;
        float sc  = gamma[j0 + jj] * rsqrtf(var + BN_EPS);
        float sh  = beta[j0 + jj] - mu * sc;
        ws[OFF_SCALE + j0 + jj] = sc;
        ws[OFF_SHIFT + j0 + jj] = sh;
    }
}

// ============ K3: category histogram ============
__global__ __launch_bounds__(256) void k3_hist(const int* __restrict__ cats,
                                               float* __restrict__ ws) {
    __shared__ int h[16];
    int tid = threadIdx.x;
    if (tid < 16) h[tid] = 0;
    __syncthreads();
    for (int n = blockIdx.x * 256 + tid; n < N_PTS; n += 64 * 256)
        atomicAdd(&h[cats[n]], 1);
    __syncthreads();
    int* wi = (int*)(ws + OFF_INT);
    if (tid < 16) atomicAdd(&wi[IO_COUNTS + tid], h[tid]);
}

// ============ K4: prefix sums (serial, tiny) ============
__global__ void k4_prefix(float* __restrict__ ws) {
    int* wi = (int*)(ws + OFF_INT);
    if (threadIdx.x == 0) {
        int co = 0, ts = 0;
        wi[IO_CATOFF] = 0; wi[IO_TILEST] = 0;
        for (int c = 0; c < 16; c++) {
            int cnt = wi[IO_COUNTS + c];
            wi[IO_CURSOR + c] = co;
            co += cnt; ts += (cnt + 63) >> 6;
            wi[IO_CATOFF + c + 1] = co;
            wi[IO_TILEST + c + 1] = ts;
        }
        wi[IO_NTILES] = ts;
    }
}

// ============ K4b: grouped scatter, two-level (block reservation + LDS ranks) ====
__global__ __launch_bounds__(256) void k4b_scatter(const int* __restrict__ cats,
                                                   float* __restrict__ ws) {
    int* wi = (int*)(ws + OFF_INT);
    __shared__ int lh[16], lbase[16];
    const int tid = threadIdx.x;
    const int n0 = blockIdx.x * 512;
    if (tid < 16) lh[tid] = 0;
    __syncthreads();
    const int cA = cats[n0 + tid];
    const int cB = cats[n0 + 256 + tid];
    atomicAdd(&lh[cA], 1);
    atomicAdd(&lh[cB], 1);
    __syncthreads();
    if (tid < 16) lbase[tid] = atomicAdd(&wi[IO_CURSOR + tid], lh[tid]);
    __syncthreads();
    if (tid < 16) lh[tid] = 0;
    __syncthreads();
    int rA = atomicAdd(&lh[cA], 1);
    wi[IO_ORDER + lbase[cA] + rA] = n0 + tid;
    int rB = atomicAdd(&lh[cB], 1);
    wi[IO_ORDER + lbase[cB] + rB] = n0 + 256 + tid;
}

// ============ K5: bf16-MFMA GEMM + BN + LeakyReLU + Wc + log_softmax + scatter ====
__global__ __launch_bounds__(256) void k5_mfma(const u16* __restrict__ Fb,
                                               const u16* __restrict__ W1T,
                                               const float* __restrict__ Wc,
                                               const float* __restrict__ bias,
                                               const int* __restrict__ shifts,
                                               const int* __restrict__ seg_lens,
                                               const float* __restrict__ ws,
                                               float* __restrict__ out) {
    const int* wi = (const int*)(ws + OFF_INT);
    const int t = blockIdx.x;
    if (t >= wi[IO_NTILES]) return;
    int c = 0;
    while (!(t >= wi[IO_TILEST + c] && t < wi[IO_TILEST + c + 1])) c++;
    const int lt = t - wi[IO_TILEST + c];
    const int base = wi[IO_CATOFF + c] + lt * 64;
    const int npts = min(64, wi[IO_COUNTS + c] - lt * 64);
    const int tid = threadIdx.x;
    const int wv = tid >> 6, ln = tid & 63;
    const int g = ln >> 4, r16 = ln & 15;

    __shared__ __align__(16) unsigned char U[65536];
    __shared__ float scl[256], shl[256], wcl[1536];
    __shared__ int plds[64];

    if (tid < 64) plds[tid] = wi[IO_ORDER + base + min(tid, npts - 1)];
    scl[tid] = ws[OFF_SCALE + c * 256 + tid];
    shl[tid] = ws[OFF_SHIFT + c * 256 + tid];
#pragma unroll
    for (int i = 0; i < 6; i++) wcl[tid + i * 256] = Wc[(size_t)c * 1536 + tid + i * 256];
    __syncthreads();

    const u16* W1Tc = W1T + (size_t)c * 65536;

#pragma unroll
    for (int s = 0; s < 8; s++) {
        int flat = s * 256 + tid;
        int pt = flat >> 5, u = flat & 31;
        const u16* src = Fb + (size_t)plds[pt] * 256 + ((u ^ (pt & 7)) << 3);
        gload_lds16(src, U + (size_t)(s * 4 + wv) * 1024);
    }
#pragma unroll
    for (int rr = 0; rr < 4; rr++) {
        int n = wv * 64 + rr * 16 + (ln >> 2);
        int q = ln & 3;
        const u16* src = W1Tc + (size_t)n * 256 + 0 + ((q ^ (n & 3)) << 3);
        gload_lds16(src, U + 32768 + (size_t)(wv * 64 + rr * 16) * 64);
    }
    __syncthreads();

    f32x4 acc[4][4];
#pragma unroll
    for (int mt = 0; mt < 4; mt++)
#pragma unroll
        for (int nt = 0; nt < 4; nt++)
#pragma unroll
            for (int i = 0; i < 4; i++) acc[mt][nt][i] = 0.f;

    int cur = 0;
    for (int kc = 0; kc < 8; kc++) {
        if (kc < 7) {
            int k0 = (kc + 1) * 32;
#pragma unroll
            for (int rr = 0; rr < 4; rr++) {
                int n = wv * 64 + rr * 16 + (ln >> 2);
                int q = ln & 3;
                const u16* src = W1Tc + (size_t)n * 256 + k0 + ((q ^ (n & 3)) << 3);
                gload_lds16(src, U + 32768 + (size_t)(cur ^ 1) * 16384
                                 + (size_t)(wv * 64 + rr * 16) * 64);
            }
        }
        bf16x8 af[4], bf[4];
#pragma unroll
        for (int mt = 0; mt < 4; mt++) {
            int row = mt * 16 + r16;
            int phys = (kc * 4 + g) ^ (row & 7);
            af[mt] = *(const bf16x8*)(U + (size_t)row * 512 + phys * 16);
        }
#pragma unroll
        for (int nt = 0; nt < 4; nt++) {
            int n = wv * 64 + nt * 16 + r16;
            int phys = g ^ (n & 3);
            bf[nt] = *(const bf16x8*)(U + 32768 + (size_t)cur * 16384
                                      + (size_t)n * 64 + phys * 16);
        }
#pragma unroll
        for (int mt = 0; mt < 4; mt++)
#pragma unroll
            for (int nt = 0; nt < 4; nt++)
                acc[mt][nt] = __builtin_amdgcn_mfma_f32_16x16x32_bf16(
                    af[mt], bf[nt], acc[mt][nt], 0, 0, 0);
        __syncthreads();
        cur ^= 1;
    }

    u16* X = (u16*)U;
#pragma unroll
    for (int mt = 0; mt < 4; mt++)
#pragma unroll
        for (int nt = 0; nt < 4; nt++) {
            int col = wv * 64 + nt * 16 + r16;
            float sc = scl[col], sh = shl[col];
#pragma unroll
            for (int i = 0; i < 4; i++) {
                int pt = mt * 16 + g * 4 + i;
                float x = acc[mt][nt][i] * sc + sh;
                x = (x >= 0.f) ? x : 0.2f * x;
                X[pt * 272 + col] = f2bf(x);
            }
        }
    __syncthreads();

    const int tm = tid & 15, tn = tid >> 4;
    float pl[4][6];
#pragma unroll
    for (int i = 0; i < 4; i++)
#pragma unroll
        for (int s = 0; s < 6; s++) pl[i][s] = 0.f;
#pragma unroll
    for (int j = 0; j < 16; j++) {
        int n = tn * 16 + j;
#pragma unroll
        for (int i = 0; i < 4; i++) {
            float x = bf2f(X[(tm * 4 + i) * 272 + n]);
#pragma unroll
            for (int s = 0; s < 6; s++) pl[i][s] += x * wcl[n * 6 + s];
        }
    }
    float* red = (float*)(U + 36864);
#pragma unroll
    for (int i = 0; i < 4; i++)
#pragma unroll
        for (int s = 0; s < 6; s++)
            red[(tn * 64 + tm * 4 + i) * 6 + s] = pl[i][s];
    __syncthreads();

    if (tid < 64 && tid < npts) {
        const int m = tid;
        float lg[6];
#pragma unroll
        for (int s = 0; s < 6; s++) lg[s] = bias[s];
        for (int w = 0; w < 16; w++)
#pragma unroll
            for (int s = 0; s < 6; s++) lg[s] += red[(w * 64 + m) * 6 + s];
        float mx = lg[0];
#pragma unroll
        for (int s = 1; s < 6; s++) mx = fmaxf(mx, lg[s]);
        float se = 0.f;
#pragma unroll
        for (int s = 0; s < 6; s++) se += expf(lg[s] - mx);
        float lse = mx + logf(se);
        const int pid = plds[m];
        const int sh = shifts[c], ln2 = seg_lens[c];
        float* orow = out + (size_t)pid * OUTK;
        for (int k = 0; k < OUTK; k++) {
            int j = k - sh;
            orow[k] = (j >= 0 && j < ln2) ? (lg[j] - lse) : 0.f;
        }
    }
}

extern "C" void kernel_launch(void* const* d_in, const int* in_sizes, int n_in,
                              void* d_out, int out_size, void* d_ws, size_t ws_size,
                              hipStream_t stream) {
    const float* F      = (const float*)d_in[0];
    const float* W1     = (const float*)d_in[1];
    const float* gamma  = (const float*)d_in[2];
    const float* beta   = (const float*)d_in[3];
    const float* Wc     = (const float*)d_in[4];
    const float* bias   = (const float*)d_in[5];
    const int*  cats    = (const int*)d_in[6];
    const int*  shifts  = (const int*)d_in[7];
    const int*  seglens = (const int*)d_in[8];
    float* out = (float*)d_out;
    float* ws  = (float*)d_ws;
    u16* Fb  = (u16*)(ws + OFF_FB);
    u16* FbT = (u16*)(ws + OFF_FBT);
    u16* W1T = (u16*)(ws + OFF_W1T);

    int nchunk = 64;
    if (ws_size < ((size_t)OFF_GP + 40960ull * 64) * 4) nchunk = 32;
    if (ws_size < ((size_t)OFF_GP + 40960ull * 32) * 4) nchunk = 16;
    const int Kc = N_PTS / nchunk;

    hipLaunchKernelGGL(k0_cvt,      dim3(2048), dim3(256), 0, stream, F, Fb, FbT);
    hipLaunchKernelGGL(k0b_w1t,     dim3(256),  dim3(256), 0, stream, W1, W1T);
    hipLaunchKernelGGL(k1_gram,     dim3(10 * nchunk), dim3(256), 0, stream, FbT, ws, nchunk, Kc);
    hipLaunchKernelGGL(k1b_colsum,  dim3(256),  dim3(256), 0, stream, FbT, ws);
    hipLaunchKernelGGL(k2a_reduce,  dim3(160),  dim3(256), 0, stream, ws, nchunk);
    hipLaunchKernelGGL(k2b_stats,   dim3(256),  dim3(256), 0, stream, W1, gamma, beta, ws);
    hipLaunchKernelGGL(k3_hist,     dim3(64),   dim3(256), 0, stream, cats, ws);
    hipLaunchKernelGGL(k4_prefix,   dim3(1),    dim3(64),  0, stream, ws);
    hipLaunchKernelGGL(k4b_scatter, dim3(64),   dim3(256), 0, stream, cats, ws);
    hipLaunchKernelGGL(k5_mfma,     dim3(528),  dim3(256), 0, stream,
                       Fb, W1T, Wc, bias, shifts, seglens, ws, out);
}

// Round 6
// 115.298 us; speedup vs baseline: 3.1110x; 1.0639x over previous
//
#include <hip/hip_runtime.h>
#include <hip/hip_bf16.h>
#include <math.h>

#define N_PTS 32768
#define IN_F  256
#define NUM_CAT 16
#define CF    4096
#define NSEG  6
#define OUTK  50
#define BN_EPS 1e-5f

typedef unsigned short u16;
typedef __attribute__((ext_vector_type(8))) short bf16x8;
typedef __attribute__((ext_vector_type(4))) float f32x4;
typedef __attribute__((ext_vector_type(8))) unsigned short u16x8;

// ---- ws layout (float offsets) ----
#define OFF_G     0u          // 256*256
#define OFF_FBAR  65536u      // 256
#define OFF_SCALE 65792u      // 4096
#define OFF_SHIFT 69888u      // 4096
#define OFF_INT   73984u      // 67 + 32768 ints -> ends 106819
#define OFF_FB    106832u     // F bf16 [32768][256]            (4194304 float slots)
#define OFF_FBT   4301136u    // F^T bf16 [256][32768]           (4194304 float slots)
#define OFF_W1T   8495440u    // W1T bf16 [16][256 n][256 k]     (524288 float slots)
#define OFF_GP    9019728u    // Gram partials [chunk][40960]
#define IO_COUNTS 0
#define IO_CATOFF 16
#define IO_TILEST 33
#define IO_NTILES 50
#define IO_CURSOR 51
#define IO_ORDER  67

__device__ __forceinline__ void gload_lds16(const void* g, void* l) {
    __builtin_amdgcn_global_load_lds(
        (const __attribute__((address_space(1))) void*)g,
        (__attribute__((address_space(3))) void*)l,
        16, 0, 0);
}
__device__ __forceinline__ u16 f2bf(float f) {
    unsigned int u = __float_as_uint(f);
    return (u16)((u + 0x7FFF + ((u >> 16) & 1)) >> 16);
}
__device__ __forceinline__ float bf2f(u16 h) {
    return __uint_as_float((unsigned int)h << 16);
}

// ============ K0: F -> Fb (row-major bf16) AND FbT (transposed bf16) ============
__global__ __launch_bounds__(256) void k0_cvt(const float* __restrict__ F,
                                              u16* __restrict__ Fb,
                                              u16* __restrict__ FbT) {
    const int pb = blockIdx.x >> 2, fb = blockIdx.x & 3;
    const int p0 = pb * 64, f0 = fb * 64;
    const int tid = threadIdx.x;
    __shared__ u16 T[64][72];
    {
        int p = tid >> 2, fq = tid & 3;
        const float* src = &F[(size_t)(p0 + p) * IN_F + f0 + fq * 16];
        u16x8 o0, o1;
        float4 v0 = *(const float4*)&src[0];
        float4 v1 = *(const float4*)&src[4];
        float4 v2 = *(const float4*)&src[8];
        float4 v3 = *(const float4*)&src[12];
        o0[0]=f2bf(v0.x); o0[1]=f2bf(v0.y); o0[2]=f2bf(v0.z); o0[3]=f2bf(v0.w);
        o0[4]=f2bf(v1.x); o0[5]=f2bf(v1.y); o0[6]=f2bf(v1.z); o0[7]=f2bf(v1.w);
        o1[0]=f2bf(v2.x); o1[1]=f2bf(v2.y); o1[2]=f2bf(v2.z); o1[3]=f2bf(v2.w);
        o1[4]=f2bf(v3.x); o1[5]=f2bf(v3.y); o1[6]=f2bf(v3.z); o1[7]=f2bf(v3.w);
        u16* dst = &Fb[(size_t)(p0 + p) * IN_F + f0 + fq * 16];
        *(u16x8*)dst = o0; *(u16x8*)&dst[8] = o1;
        *(u16x8*)&T[p][fq * 16] = o0; *(u16x8*)&T[p][fq * 16 + 8] = o1;
    }
    __syncthreads();
    {
        int f = tid >> 2, pq = tid & 3;
        u16x8 a0, a1;
#pragma unroll
        for (int m = 0; m < 8; m++) { a0[m] = T[pq*16 + m][f]; a1[m] = T[pq*16 + 8 + m][f]; }
        u16* dst = &FbT[(size_t)(f0 + f) * N_PTS + p0 + pq * 16];
        *(u16x8*)dst = a0; *(u16x8*)&dst[8] = a1;
    }
}

// ============ K0b: W1 [256][4096] -> W1T bf16 [c][n][k] ============
__global__ __launch_bounds__(256) void k0b_w1t(const float* __restrict__ W1,
                                               u16* __restrict__ W1T) {
    __shared__ u16 T[64][65];
    const int kb = blockIdx.x & 3, jb = blockIdx.x >> 2;
    const int tid = threadIdx.x;
    {
        int kk = tid >> 2, j4 = (tid & 3) * 16;
        const float* src = &W1[(size_t)(kb * 64 + kk) * CF + jb * 64 + j4];
#pragma unroll
        for (int q = 0; q < 4; q++) {
            float4 v = *(const float4*)&src[q * 4];
            T[kk][j4 + q * 4 + 0] = f2bf(v.x); T[kk][j4 + q * 4 + 1] = f2bf(v.y);
            T[kk][j4 + q * 4 + 2] = f2bf(v.z); T[kk][j4 + q * 4 + 3] = f2bf(v.w);
        }
    }
    __syncthreads();
    {
        int jj = tid >> 2, ks = (tid & 3) * 16;
        int c = jb >> 2, n = (jb & 3) * 64 + jj;
        u16* dst = &W1T[((size_t)(c * 256 + n)) * 256 + kb * 64 + ks];
        u16x8 o0, o1;
#pragma unroll
        for (int m = 0; m < 8; m++) { o0[m] = T[ks + m][jj]; o1[m] = T[ks + 8 + m][jj]; }
        *(u16x8*)dst = o0;
        *(u16x8*)&dst[8] = o1;
    }
}

// ============ K1: Gram via bf16 MFMA (10 symmetric tiles x nchunk K-chunks) ============
__global__ __launch_bounds__(256) void k1_gram(const u16* __restrict__ FbT,
                                               float* __restrict__ ws,
                                               int nchunk, int Kc) {
    const int TI[10] = {0,0,0,0,1,1,1,2,2,3};
    const int TJ[10] = {0,1,2,3,1,2,3,2,3,3};
    const int t = blockIdx.x % 10, chunk = blockIdx.x / 10;
    const int i0 = TI[t] * 64, j0 = TJ[t] * 64;
    const int r0 = chunk * Kc;
    const int tid = threadIdx.x;
    const int wv = tid >> 6, ln = tid & 63, g = ln >> 4, r16 = ln & 15;
    __shared__ __align__(16) u16 SA[2][4096];
    __shared__ __align__(16) u16 SB[2][4096];

    const int q0 = wv * 2, q1 = wv * 2 + 1;
    const int u_a = ((q0 * 64 + ln) & 7), row_a = (q0 * 64 + ln) >> 3;
    const int u_b = ((q1 * 64 + ln) & 7), row_b = (q1 * 64 + ln) >> 3;
    const int ka = ((u_a ^ (row_a & 7)) << 3), kb2 = ((u_b ^ (row_b & 7)) << 3);

    f32x4 acc[4];
#pragma unroll
    for (int nt = 0; nt < 4; nt++)
#pragma unroll
        for (int i = 0; i < 4; i++) acc[nt][i] = 0.f;

    const int nslab = Kc >> 6;
#define K1_STAGE(s, b)                                                              \
    {   int p0s = r0 + (s) * 64;                                                    \
        gload_lds16(FbT + (size_t)(i0 + row_a) * N_PTS + p0s + ka,                  \
                    (char*)SA[b] + q0 * 1024);                                      \
        gload_lds16(FbT + (size_t)(i0 + row_b) * N_PTS + p0s + kb2,                 \
                    (char*)SA[b] + q1 * 1024);                                      \
        gload_lds16(FbT + (size_t)(j0 + row_a) * N_PTS + p0s + ka,                  \
                    (char*)SB[b] + q0 * 1024);                                      \
        gload_lds16(FbT + (size_t)(j0 + row_b) * N_PTS + p0s + kb2,                 \
                    (char*)SB[b] + q1 * 1024);                                      \
    }

    K1_STAGE(0, 0);
    __syncthreads();
    for (int s = 0; s < nslab; s++) {
        const int b = s & 1;
        if (s + 1 < nslab) K1_STAGE(s + 1, b ^ 1);
#pragma unroll
        for (int ks = 0; ks < 2; ks++) {
            int ph = (ks * 4 + g) ^ (r16 & 7);
            bf16x8 a = *(const bf16x8*)((const char*)SA[b] + (wv * 16 + r16) * 128 + ph * 16);
#pragma unroll
            for (int nt = 0; nt < 4; nt++) {
                int nB = nt * 16 + r16;
                bf16x8 bb = *(const bf16x8*)((const char*)SB[b] + nB * 128 + ph * 16);
                acc[nt] = __builtin_amdgcn_mfma_f32_16x16x32_bf16(a, bb, acc[nt], 0, 0, 0);
            }
        }
        __syncthreads();
    }
    float* Gp = ws + OFF_GP + (size_t)chunk * 40960 + t * 4096;
#pragma unroll
    for (int nt = 0; nt < 4; nt++)
#pragma unroll
        for (int i = 0; i < 4; i++) {
            int row = wv * 16 + g * 4 + i, col = nt * 16 + r16;
            Gp[row * 64 + col] = acc[nt][i];
        }
}

// ============ K1b: column means from FbT; zero category counts ============
__global__ __launch_bounds__(256) void k1b_colsum(const u16* __restrict__ FbT,
                                                  float* __restrict__ ws) {
    const int row = blockIdx.x, tid = threadIdx.x;
    const u16* r = FbT + (size_t)row * N_PTS;
    float s = 0.f;
    for (int i = tid * 8; i < N_PTS; i += 2048) {
        u16x8 v = *(const u16x8*)&r[i];
#pragma unroll
        for (int m = 0; m < 8; m++) s += bf2f(v[m]);
    }
#pragma unroll
    for (int off = 32; off >= 1; off >>= 1) s += __shfl_xor(s, off);
    __shared__ float ps[4];
    if ((tid & 63) == 0) ps[tid >> 6] = s;
    __syncthreads();
    if (tid == 0) ws[OFF_FBAR + row] = (ps[0] + ps[1] + ps[2] + ps[3]) * (1.0f / N_PTS);
    if (blockIdx.x == 0 && tid < 16) ((int*)(ws + OFF_INT))[IO_COUNTS + tid] = 0;
}

// ============ K2a: coalesced reduce of Gram partials -> symmetric G ============
__global__ __launch_bounds__(256) void k2a_reduce(float* __restrict__ ws, int nchunk) {
    const int TI[10] = {0,0,0,0,1,1,1,2,2,3};
    const int TJ[10] = {0,1,2,3,1,2,3,2,3,3};
    const int e = blockIdx.x * 256 + threadIdx.x;   // 0..40959
    const float* p = ws + OFF_GP + e;
    float s = 0.f;
#pragma unroll 8
    for (int c = 0; c < nchunk; c++) s += p[(size_t)c * 40960];
    int t = e >> 12, x = (e >> 6) & 63, y = e & 63;
    int a = TI[t] * 64 + x, b = TJ[t] * 64 + y;
    ws[OFF_G + a * 256 + b] = s;
    ws[OFF_G + b * 256 + a] = s;
}

// ============ K2b: per-column mu/var -> scale/shift ============
__global__ __launch_bounds__(256) void k2b_stats(const float* __restrict__ W1,
                                                 const float* __restrict__ gamma,
                                                 const float* __restrict__ beta,
                                                 float* __restrict__ ws) {
    const int tid = threadIdx.x;
    const int j0 = blockIdx.x * 16;
    __shared__ __align__(16) float wl[16][256];
    __shared__ float pw[16][8];
#pragma unroll
    for (int q = 0; q < 4; q++) {
        float4 v = *(const float4*)&W1[(size_t)tid * CF + j0 + q * 4];
        wl[q * 4 + 0][tid] = v.x; wl[q * 4 + 1][tid] = v.y;
        wl[q * 4 + 2][tid] = v.z; wl[q * 4 + 3][tid] = v.w;
    }
    __syncthreads();
    float acc[16];
#pragma unroll
    for (int jj = 0; jj < 16; jj++) acc[jj] = 0.f;
    const float* G = ws + OFF_G;
    for (int b = 0; b < 256; b++) {
        float g = G[b * 256 + tid];
#pragma unroll
        for (int jj = 0; jj < 16; jj++) acc[jj] += g * wl[jj][b];
    }
    float fb = ws[OFF_FBAR + tid];
    const int lane = tid & 63, wave = tid >> 6;
#pragma unroll
    for (int jj = 0; jj < 16; jj++) {
        float v = wl[jj][tid] * acc[jj];
        float m = fb * wl[jj][tid];
#pragma unroll
        for (int off = 32; off >= 1; off >>= 1) {
            v += __shfl_xor(v, off);
            m += __shfl_xor(m, off);
        }
        if (lane == 0) { pw[jj][wave * 2] = v; pw[jj][wave * 2 + 1] = m; }
    }
    __syncthreads();
    if (tid < 16) {
        int jj = tid;
        float v = 0.f, m = 0.f;
        for (int w2 = 0; w2 < 4; w2++) { v += pw[jj][w2 * 2]; m += pw[jj][w2 * 2 + 1]; }
        float mu  = m;
        float var = v * (1.0f / N_PTS) - mu * mu;
        float sc  = gamma[j0 + jj] * rsqrtf(var + BN_EPS);
        float sh  = beta[j0 + jj] - mu * sc;
        ws[OFF_SCALE + j0 + jj] = sc;
        ws[OFF_SHIFT + j0 + jj] = sh;
    }
}

// ============ K3: category histogram ============
__global__ __launch_bounds__(256) void k3_hist(const int* __restrict__ cats,
                                               float* __restrict__ ws) {
    __shared__ int h[16];
    int tid = threadIdx.x;
    if (tid < 16) h[tid] = 0;
    __syncthreads();
    for (int n = blockIdx.x * 256 + tid; n < N_PTS; n += 64 * 256)
        atomicAdd(&h[cats[n]], 1);
    __syncthreads();
    int* wi = (int*)(ws + OFF_INT);
    if (tid < 16) atomicAdd(&wi[IO_COUNTS + tid], h[tid]);
}

// ============ K4: prefix sums (serial, tiny) ============
__global__ void k4_prefix(float* __restrict__ ws) {
    int* wi = (int*)(ws + OFF_INT);
    if (threadIdx.x == 0) {
        int co = 0, ts = 0;
        wi[IO_CATOFF] = 0; wi[IO_TILEST] = 0;
        for (int c = 0; c < 16; c++) {
            int cnt = wi[IO_COUNTS + c];
            wi[IO_CURSOR + c] = co;
            co += cnt; ts += (cnt + 63) >> 6;
            wi[IO_CATOFF + c + 1] = co;
            wi[IO_TILEST + c + 1] = ts;
        }
        wi[IO_NTILES] = ts;
    }
}

// ============ K4b: grouped scatter, two-level (block reservation + LDS ranks) ====
__global__ __launch_bounds__(256) void k4b_scatter(const int* __restrict__ cats,
                                                   float* __restrict__ ws) {
    int* wi = (int*)(ws + OFF_INT);
    __shared__ int lh[16], lbase[16];
    const int tid = threadIdx.x;
    const int n0 = blockIdx.x * 512;
    if (tid < 16) lh[tid] = 0;
    __syncthreads();
    const int cA = cats[n0 + tid];
    const int cB = cats[n0 + 256 + tid];
    atomicAdd(&lh[cA], 1);
    atomicAdd(&lh[cB], 1);
    __syncthreads();
    if (tid < 16) lbase[tid] = atomicAdd(&wi[IO_CURSOR + tid], lh[tid]);
    __syncthreads();
    if (tid < 16) lh[tid] = 0;
    __syncthreads();
    int rA = atomicAdd(&lh[cA], 1);
    wi[IO_ORDER + lbase[cA] + rA] = n0 + tid;
    int rB = atomicAdd(&lh[cB], 1);
    wi[IO_ORDER + lbase[cB] + rB] = n0 + 256 + tid;
}

// ============ K5: bf16-MFMA GEMM, barrier-free K-loop ============
// F tile (64pt x 256k) staged once in LDS (swizzled). W fragments loaded
// straight from L2-resident W1T into registers, 2-deep pipeline, full unroll.
// Epilogue: BN+LeakyReLU+Wc partials in-register, shfl-reduced across 16 lanes,
// tiny red2[64][4][6] in LDS (overlaps dead F tile).
__global__ __launch_bounds__(256) void k5_mfma(const u16* __restrict__ Fb,
                                               const u16* __restrict__ W1T,
                                               const float* __restrict__ Wc,
                                               const float* __restrict__ bias,
                                               const int* __restrict__ shifts,
                                               const int* __restrict__ seg_lens,
                                               const float* __restrict__ ws,
                                               float* __restrict__ out) {
    const int* wi = (const int*)(ws + OFF_INT);
    const int t = blockIdx.x;
    if (t >= wi[IO_NTILES]) return;
    int c = 0;
    while (!(t >= wi[IO_TILEST + c] && t < wi[IO_TILEST + c + 1])) c++;
    const int lt = t - wi[IO_TILEST + c];
    const int base = wi[IO_CATOFF + c] + lt * 64;
    const int npts = min(64, wi[IO_COUNTS + c] - lt * 64);
    const int tid = threadIdx.x;
    const int wv = tid >> 6, ln = tid & 63;
    const int g = ln >> 4, r16 = ln & 15;

    __shared__ __align__(16) unsigned char U[32768];   // F tile; reused as red2
    __shared__ float scl[256], shl[256], wcl[1536];
    __shared__ int plds[64];

    if (tid < 64) plds[tid] = wi[IO_ORDER + base + min(tid, npts - 1)];
    scl[tid] = ws[OFF_SCALE + c * 256 + tid];
    shl[tid] = ws[OFF_SHIFT + c * 256 + tid];
#pragma unroll
    for (int i = 0; i < 6; i++) wcl[tid + i * 256] = Wc[(size_t)c * 1536 + tid + i * 256];
    __syncthreads();

    // ---- stage F tile once: row pt at byte pt*512, 16B units permuted by ^(pt&7) ----
#pragma unroll
    for (int s = 0; s < 8; s++) {
        int flat = s * 256 + tid;
        int pt = flat >> 5, u = flat & 31;
        const u16* src = Fb + (size_t)plds[pt] * 256 + ((u ^ (pt & 7)) << 3);
        gload_lds16(src, U + (size_t)(s * 4 + wv) * 1024);
    }
    __syncthreads();   // F ready (drains gload_lds)

    const u16* W1Tc = W1T + (size_t)c * 65536;
    const u16* wp0 = W1Tc + (size_t)(wv * 64 +  0 + r16) * 256 + g * 8;
    const u16* wp1 = W1Tc + (size_t)(wv * 64 + 16 + r16) * 256 + g * 8;
    const u16* wp2 = W1Tc + (size_t)(wv * 64 + 32 + r16) * 256 + g * 8;
    const u16* wp3 = W1Tc + (size_t)(wv * 64 + 48 + r16) * 256 + g * 8;

    f32x4 acc[4][4];
#pragma unroll
    for (int mt = 0; mt < 4; mt++)
#pragma unroll
        for (int nt = 0; nt < 4; nt++)
#pragma unroll
            for (int i = 0; i < 4; i++) acc[mt][nt][i] = 0.f;

    bf16x8 bf[2][4];
    bf[0][0] = *(const bf16x8*)(wp0);
    bf[0][1] = *(const bf16x8*)(wp1);
    bf[0][2] = *(const bf16x8*)(wp2);
    bf[0][3] = *(const bf16x8*)(wp3);

#pragma unroll
    for (int kc = 0; kc < 8; kc++) {
        if (kc < 7) {   // prefetch next chunk's W fragments (static slot kc^1 via unroll)
            bf[(kc + 1) & 1][0] = *(const bf16x8*)(wp0 + (kc + 1) * 32);
            bf[(kc + 1) & 1][1] = *(const bf16x8*)(wp1 + (kc + 1) * 32);
            bf[(kc + 1) & 1][2] = *(const bf16x8*)(wp2 + (kc + 1) * 32);
            bf[(kc + 1) & 1][3] = *(const bf16x8*)(wp3 + (kc + 1) * 32);
        }
        bf16x8 af[4];
#pragma unroll
        for (int mt = 0; mt < 4; mt++) {
            int row = mt * 16 + r16;
            int phys = (kc * 4 + g) ^ (row & 7);
            af[mt] = *(const bf16x8*)(U + (size_t)row * 512 + phys * 16);
        }
#pragma unroll
        for (int mt = 0; mt < 4; mt++)
#pragma unroll
            for (int nt = 0; nt < 4; nt++)
                acc[mt][nt] = __builtin_amdgcn_mfma_f32_16x16x32_bf16(
                    af[mt], bf[kc & 1][nt], acc[mt][nt], 0, 0, 0);
    }

    __syncthreads();   // all waves done reading F from U
    float* red2 = (float*)U;   // [64 pt][4 wv][6]
#pragma unroll
    for (int mt = 0; mt < 4; mt++)
#pragma unroll
        for (int i = 0; i < 4; i++) {
            float pl[6] = {0.f, 0.f, 0.f, 0.f, 0.f, 0.f};
#pragma unroll
            for (int nt = 0; nt < 4; nt++) {
                int col = wv * 64 + nt * 16 + r16;
                float x = acc[mt][nt][i] * scl[col] + shl[col];
                x = (x >= 0.f) ? x : 0.2f * x;
#pragma unroll
                for (int s = 0; s < 6; s++) pl[s] += x * wcl[col * 6 + s];
            }
#pragma unroll
            for (int s = 0; s < 6; s++) {
                pl[s] += __shfl_xor(pl[s], 1);
                pl[s] += __shfl_xor(pl[s], 2);
                pl[s] += __shfl_xor(pl[s], 4);
                pl[s] += __shfl_xor(pl[s], 8);
            }
            if (r16 == 0) {
                int pt = mt * 16 + g * 4 + i;
#pragma unroll
                for (int s = 0; s < 6; s++) red2[(pt * 4 + wv) * 6 + s] = pl[s];
            }
        }
    __syncthreads();

    if (tid < 64 && tid < npts) {
        float lg[6];
#pragma unroll
        for (int s = 0; s < 6; s++) lg[s] = bias[s];
#pragma unroll
        for (int w = 0; w < 4; w++)
#pragma unroll
            for (int s = 0; s < 6; s++) lg[s] += red2[(tid * 4 + w) * 6 + s];
        float mx = lg[0];
#pragma unroll
        for (int s = 1; s < 6; s++) mx = fmaxf(mx, lg[s]);
        float se = 0.f;
#pragma unroll
        for (int s = 0; s < 6; s++) se += expf(lg[s] - mx);
        float lse = mx + logf(se);
        const int pid = plds[tid];
        const int sh = shifts[c], ln2 = seg_lens[c];
        float* orow = out + (size_t)pid * OUTK;
        for (int k = 0; k < OUTK; k++) {
            int j = k - sh;
            orow[k] = (j >= 0 && j < ln2) ? (lg[j] - lse) : 0.f;
        }
    }
}

extern "C" void kernel_launch(void* const* d_in, const int* in_sizes, int n_in,
                              void* d_out, int out_size, void* d_ws, size_t ws_size,
                              hipStream_t stream) {
    const float* F      = (const float*)d_in[0];
    const float* W1     = (const float*)d_in[1];
    const float* gamma  = (const float*)d_in[2];
    const float* beta   = (const float*)d_in[3];
    const float* Wc     = (const float*)d_in[4];
    const float* bias   = (const float*)d_in[5];
    const int*  cats    = (const int*)d_in[6];
    const int*  shifts  = (const int*)d_in[7];
    const int*  seglens = (const int*)d_in[8];
    float* out = (float*)d_out;
    float* ws  = (float*)d_ws;
    u16* Fb  = (u16*)(ws + OFF_FB);
    u16* FbT = (u16*)(ws + OFF_FBT);
    u16* W1T = (u16*)(ws + OFF_W1T);

    int nchunk = 64;
    if (ws_size < ((size_t)OFF_GP + 40960ull * 64) * 4) nchunk = 32;
    if (ws_size < ((size_t)OFF_GP + 40960ull * 32) * 4) nchunk = 16;
    const int Kc = N_PTS / nchunk;

    hipLaunchKernelGGL(k0_cvt,      dim3(2048), dim3(256), 0, stream, F, Fb, FbT);
    hipLaunchKernelGGL(k0b_w1t,     dim3(256),  dim3(256), 0, stream, W1, W1T);
    hipLaunchKernelGGL(k1_gram,     dim3(10 * nchunk), dim3(256), 0, stream, FbT, ws, nchunk, Kc);
    hipLaunchKernelGGL(k1b_colsum,  dim3(256),  dim3(256), 0, stream, FbT, ws);
    hipLaunchKernelGGL(k2a_reduce,  dim3(160),  dim3(256), 0, stream, ws, nchunk);
    hipLaunchKernelGGL(k2b_stats,   dim3(256),  dim3(256), 0, stream, W1, gamma, beta, ws);
    hipLaunchKernelGGL(k3_hist,     dim3(64),   dim3(256), 0, stream, cats, ws);
    hipLaunchKernelGGL(k4_prefix,   dim3(1),    dim3(64),  0, stream, ws);
    hipLaunchKernelGGL(k4b_scatter, dim3(64),   dim3(256), 0, stream, cats, ws);
    hipLaunchKernelGGL(k5_mfma,     dim3(528),  dim3(256), 0, stream,
                       Fb, W1T, Wc, bias, shifts, seglens, ws, out);
}